// Round 12
// baseline (28.240 us; speedup 1.0000x reference)
//
#include <hip/hip_runtime.h>
#include <hip/hip_bf16.h>

#define B_ 8
#define G_ 1024
#define HD_ 1024
#define EPS_ 1e-5f

// NOTE: The reference's BatchNorm over the G axis (training mode, batch stats)
// makes the output invariant to any per-(b,j) constant added to H @ fc_w.T.
// The broadcast-qemb half of H and fc_b are such constants -> the whole GIN
// pipeline cannot affect d_out. Only gPos, allDBGEmb, fc_w[:,1024:], bn3, fc2
// matter. (Verified R3 vs R4: identical absmax.)
// R5/R8: ANY grid-wide sync costs 27-45 us -> kernel boundaries are cheapest.
// R7: keep stage/compute overlap (double-buffer); single-stage loses ~4 us.
// R9/R10: fused-tail lost 3/3 -> keep separate k_stats + k_final. f32 z.
// R11: 2 blocks/CU (16g tiles) won 29.0 -> 27.3.
// R12 change: BK 128 -> 256 (4 phases, half the vmcnt-draining barriers,
// 2x in-flight gather per phase).

typedef __attribute__((ext_vector_type(8))) short bf16x8;
typedef __attribute__((ext_vector_type(4))) short bf16x4;
typedef __attribute__((ext_vector_type(4))) float f32x4;

__device__ inline short bf1(float x) {
    return (short)__builtin_bit_cast(unsigned short, __float2bfloat16(x));
}
__device__ inline bf16x8 cvt8(float4 a, float4 b) {
    bf16x8 o;
    o[0] = bf1(a.x); o[1] = bf1(a.y); o[2] = bf1(a.z); o[3] = bf1(a.w);
    o[4] = bf1(b.x); o[5] = bf1(b.y); o[6] = bf1(b.z); o[7] = bf1(b.w);
    return o;
}
__device__ inline bf16x4 cvt4(float4 a) {
    bf16x4 o;
    o[0] = bf1(a.x); o[1] = bf1(a.y); o[2] = bf1(a.z); o[3] = bf1(a.w);
    return o;
}

// ---------- fc_w[:,1024:2048] -> bf16 in MFMA B-fragment order ----------
// frag f = kt*8 + jblk (kt = k/32, jblk = j/16); lane l holds
// B[k = kt*32 + (l>>4)*8 + i][j = jblk*16 + (l&15)], i = 0..7.
__global__ __launch_bounds__(256) void k_w2cvt(const float* __restrict__ fc_w,
                                               short* __restrict__ w2arr) {
    int gid = blockIdx.x * 256 + threadIdx.x;  // 0 .. 32*8*64-1
    int kt = gid >> 9;
    int jblk = (gid >> 6) & 7;
    int lane = gid & 63;
    int j = jblk * 16 + (lane & 15);
    int k = kt * 32 + (lane >> 4) * 8;
    const float4* sp = (const float4*)&fc_w[(size_t)j * (2 * HD_) + HD_ + k];
    *(bf16x8*)&w2arr[(size_t)gid * 8] = cvt8(sp[0], sp[1]);
}

#define SLAB16 130  // 16 rows * 8 shorts + 2 pad per 8-k slab

// ---------- z[b][g][j] = emb[gPos[b][g]] . fc_w[j][1024:2048] ----------
// grid (64, 8) = 512 blocks (2/CU), 512 thr = 8 waves; wave jq = 0..7 does
// 16g x 16j via 16x16x32 MFMA. A: LDS double-buffered 16-row BK=256 tile
// (16.6 KB total). B: one fragment per kt per wave, direct from w2arr (L2).
__global__ __launch_bounds__(512) void k_gemm(const int* __restrict__ gPos,
                                              const float* __restrict__ emb,
                                              const short* __restrict__ w2arr,
                                              float* __restrict__ z,
                                              float* __restrict__ ps,
                                              float* __restrict__ pq) {
    int b = blockIdx.y, gblk = blockIdx.x;
    int gbase = gblk * 16;
    int tid = threadIdx.x;
    int jq = tid >> 6, lane = tid & 63;
    int l15 = lane & 15, kb = lane >> 4;  // kb = 0..3

    __shared__ int gidx[16];
    __shared__ short As[2][32 * SLAB16];

    if (tid < 16) gidx[tid] = gPos[b * G_ + gbase + tid];
    __syncthreads();

    int arow = tid >> 5, acp = tid & 31;  // 2 float4 (2x 4k) per thread per phase
    const float* abase = emb + (size_t)gidx[arow] * HD_;
    int aoff1 = (acp >> 1) * SLAB16 + arow * 8 + (acp & 1) * 4;
    int aoff2 = (16 + (acp >> 1)) * SLAB16 + arow * 8 + (acp & 1) * 4;

    f32x4 acc = {0.f, 0.f, 0.f, 0.f};

    {   // prologue: stage phase 0 (k 0..255)
        float4 av1 = *(const float4*)(abase + acp * 4);
        float4 av2 = *(const float4*)(abase + 128 + acp * 4);
        *(bf16x4*)&As[0][aoff1] = cvt4(av1);
        *(bf16x4*)&As[0][aoff2] = cvt4(av2);
    }
    __syncthreads();

    for (int p = 0; p < 4; ++p) {
        int cur = p & 1;
        if (p < 3) {
            const float* ab = abase + (p + 1) * 256;
            float4 av1 = *(const float4*)(ab + acp * 4);
            float4 av2 = *(const float4*)(ab + 128 + acp * 4);
            *(bf16x4*)&As[cur ^ 1][aoff1] = cvt4(av1);
            *(bf16x4*)&As[cur ^ 1][aoff2] = cvt4(av2);
        }
#pragma unroll
        for (int kt = 0; kt < 8; ++kt) {
            int f = (p * 8 + kt) * 8 + jq;
            bf16x8 bv = *(const bf16x8*)&w2arr[((size_t)f * 64 + lane) * 8];
            bf16x8 a = *(const bf16x8*)&As[cur][(kt * 4 + kb) * SLAB16 + l15 * 8];
            acc = __builtin_amdgcn_mfma_f32_16x16x32_bf16(a, bv, acc, 0, 0, 0);
        }
        __syncthreads();
    }

    // epilogue: f32 z write + per-(b,gblk) BN partials
    int jcol = jq * 16 + l15;
    float s = 0.f, q = 0.f;
#pragma unroll
    for (int r = 0; r < 4; ++r) {  // C/D: col=lane&15, row=(lane>>4)*4+r
        float v = acc[r];
        int g = gbase + kb * 4 + r;
        z[(size_t)(b * G_ + g) * 128 + jcol] = v;
        s += v;
        q += v * v;
    }
    s += __shfl_xor(s, 16, 64); s += __shfl_xor(s, 32, 64);
    q += __shfl_xor(q, 16, 64); q += __shfl_xor(q, 32, 64);
    if (lane < 16) {
        ps[(b * 64 + gblk) * 128 + jcol] = s;
        pq[(b * 64 + gblk) * 128 + jcol] = q;
    }
}

// ---------- BN3 stats: reduce 64 block-partials -> scale/shift per (b,j) ----------
__global__ void k_stats(const float* __restrict__ ps, const float* __restrict__ pq,
                        const float* __restrict__ g3, const float* __restrict__ b3,
                        float* __restrict__ scv, float* __restrict__ shv) {
    int b = blockIdx.x, j = threadIdx.x;
    float s = 0.f, q = 0.f;
#pragma unroll 8
    for (int t = 0; t < 64; ++t) {
        s += ps[(b * 64 + t) * 128 + j];
        q += pq[(b * 64 + t) * 128 + j];
    }
    float mu = s * (1.f / G_);
    float var = q * (1.f / G_) - mu * mu;
    float sc = g3[j] * rsqrtf(var + EPS_);
    scv[b * 128 + j] = sc;
    shv[b * 128 + j] = b3[j] - mu * sc;
}

// ---------- BN3 apply + relu + fc2 dot + sigmoid; one wave per (b,g) ----------
__global__ __launch_bounds__(256) void k_final(const float* __restrict__ z,
                                               const float* __restrict__ scv,
                                               const float* __restrict__ shv,
                                               const float* __restrict__ fc2w,
                                               const float* __restrict__ fc2b,
                                               float* __restrict__ out) {
    int wid = (blockIdx.x * blockDim.x + threadIdx.x) >> 6;
    int lane = threadIdx.x & 63;
    int b = wid >> 10;
    const float* zr = z + (size_t)wid * 128;
    float acc = 0.f;
#pragma unroll
    for (int t = 0; t < 2; ++t) {
        int j = lane + t * 64;
        float v = fmaf(zr[j], scv[b * 128 + j], shv[b * 128 + j]);
        v = fmaxf(v, 0.f);
        acc += v * fc2w[j];
    }
    for (int off = 32; off; off >>= 1) acc += __shfl_down(acc, off, 64);
    if (lane == 0) out[wid] = 1.f / (1.f + expf(-(acc + fc2b[0])));
}

extern "C" void kernel_launch(void* const* d_in, const int* in_sizes, int n_in,
                              void* d_out, int out_size, void* d_ws, size_t ws_size,
                              hipStream_t stream) {
    const int*   gPos = (const int*)d_in[3];
    const float* emb  = (const float*)d_in[4];
    const float* fc_w = (const float*)d_in[11];
    const float* bn3g = (const float*)d_in[13];
    const float* bn3b = (const float*)d_in[14];
    const float* fc2w = (const float*)d_in[15];
    const float* fc2b = (const float*)d_in[16];
    float* out = (float*)d_out;

    char* w = (char*)d_ws;
    float* z     = (float*)w; w += (size_t)B_ * G_ * 128 * 4;   // 4 MB
    short* w2arr = (short*)w; w += (size_t)128 * HD_ * 2;       // 256 KB
    float* ps    = (float*)w; w += (size_t)B_ * 64 * 128 * 4;   // 256 KB
    float* pq    = (float*)w; w += (size_t)B_ * 64 * 128 * 4;   // 256 KB
    float* scv   = (float*)w; w += (size_t)B_ * 128 * 4;
    float* shv   = (float*)w; w += (size_t)B_ * 128 * 4;

    k_w2cvt<<<64, 256, 0, stream>>>(fc_w, w2arr);
    k_gemm<<<dim3(64, B_), 512, 0, stream>>>(gPos, emb, w2arr, z, ps, pq);
    k_stats<<<B_, 128, 0, stream>>>(ps, pq, bn3g, bn3b, scv, shv);
    k_final<<<(B_ * G_) / 4, 256, 0, stream>>>(z, scv, shv, fc2w, fc2b, out);
}

// Round 13
// 27.071 us; speedup vs baseline: 1.0432x; 1.0432x over previous
//
#include <hip/hip_runtime.h>
#include <hip/hip_bf16.h>

#define B_ 8
#define G_ 1024
#define HD_ 1024
#define EPS_ 1e-5f

// NOTE: The reference's BatchNorm over the G axis (training mode, batch stats)
// makes the output invariant to any per-(b,j) constant added to H @ fc_w.T.
// The broadcast-qemb half of H and fc_b are such constants -> the whole GIN
// pipeline cannot affect d_out. Only gPos, allDBGEmb, fc_w[:,1024:], bn3, fc2
// matter. (Verified R3 vs R4: identical absmax.)
// R5/R8: ANY grid-wide sync costs 27-45 us -> kernel boundaries are cheapest.
// R7: keep stage/compute overlap (double-buffer); single-stage loses ~4 us.
// R9/R10: fused-tail lost 3/3 -> keep separate k_stats + k_final. f32 z.
// R11: 2 blocks/CU (16g tiles) won 29.0 -> 27.3 (best).
// R12: BK=256 within noise (28.2) -> barrier lever exhausted; this file is
// R11 verbatim (best-measured config, final).

typedef __attribute__((ext_vector_type(8))) short bf16x8;
typedef __attribute__((ext_vector_type(4))) short bf16x4;
typedef __attribute__((ext_vector_type(4))) float f32x4;

__device__ inline short bf1(float x) {
    return (short)__builtin_bit_cast(unsigned short, __float2bfloat16(x));
}
__device__ inline bf16x8 cvt8(float4 a, float4 b) {
    bf16x8 o;
    o[0] = bf1(a.x); o[1] = bf1(a.y); o[2] = bf1(a.z); o[3] = bf1(a.w);
    o[4] = bf1(b.x); o[5] = bf1(b.y); o[6] = bf1(b.z); o[7] = bf1(b.w);
    return o;
}
__device__ inline bf16x4 cvt4(float4 a) {
    bf16x4 o;
    o[0] = bf1(a.x); o[1] = bf1(a.y); o[2] = bf1(a.z); o[3] = bf1(a.w);
    return o;
}

// ---------- fc_w[:,1024:2048] -> bf16 in MFMA B-fragment order ----------
// frag f = kt*8 + jblk (kt = k/32, jblk = j/16); lane l holds
// B[k = kt*32 + (l>>4)*8 + i][j = jblk*16 + (l&15)], i = 0..7.
__global__ __launch_bounds__(256) void k_w2cvt(const float* __restrict__ fc_w,
                                               short* __restrict__ w2arr) {
    int gid = blockIdx.x * 256 + threadIdx.x;  // 0 .. 32*8*64-1
    int kt = gid >> 9;
    int jblk = (gid >> 6) & 7;
    int lane = gid & 63;
    int j = jblk * 16 + (lane & 15);
    int k = kt * 32 + (lane >> 4) * 8;
    const float4* sp = (const float4*)&fc_w[(size_t)j * (2 * HD_) + HD_ + k];
    *(bf16x8*)&w2arr[(size_t)gid * 8] = cvt8(sp[0], sp[1]);
}

#define SLAB16 130  // 16 rows * 8 shorts + 2 pad per 8-k slab

// ---------- z[b][g][j] = emb[gPos[b][g]] . fc_w[j][1024:2048] ----------
// grid (64, 8) = 512 blocks (2/CU), 512 thr = 8 waves; wave jq = 0..7 does
// 16g x 16j via 16x16x32 MFMA. A: LDS double-buffered 16-row tile (8.3 KB).
// B: one fragment per kt per wave, direct from w2arr (L2).
__global__ __launch_bounds__(512) void k_gemm(const int* __restrict__ gPos,
                                              const float* __restrict__ emb,
                                              const short* __restrict__ w2arr,
                                              float* __restrict__ z,
                                              float* __restrict__ ps,
                                              float* __restrict__ pq) {
    int b = blockIdx.y, gblk = blockIdx.x;
    int gbase = gblk * 16;
    int tid = threadIdx.x;
    int jq = tid >> 6, lane = tid & 63;
    int l15 = lane & 15, kb = lane >> 4;  // kb = 0..3

    __shared__ int gidx[16];
    __shared__ short As[2][16 * SLAB16];

    if (tid < 16) gidx[tid] = gPos[b * G_ + gbase + tid];
    __syncthreads();

    int arow = tid >> 5, acp = tid & 31;  // one float4 (4 k) per thread per phase
    const float* abase = emb + (size_t)gidx[arow] * HD_;
    int aoff = (acp >> 1) * SLAB16 + arow * 8 + (acp & 1) * 4;

    f32x4 acc = {0.f, 0.f, 0.f, 0.f};

    {   // prologue: stage phase 0
        float4 av = *(const float4*)(abase + acp * 4);
        *(bf16x4*)&As[0][aoff] = cvt4(av);
    }
    __syncthreads();

    for (int p = 0; p < 8; ++p) {
        int cur = p & 1;
        if (p < 7) {
            float4 av = *(const float4*)(abase + (p + 1) * 128 + acp * 4);
            *(bf16x4*)&As[cur ^ 1][aoff] = cvt4(av);
        }
#pragma unroll
        for (int kt = 0; kt < 4; ++kt) {
            int f = (p * 4 + kt) * 8 + jq;
            bf16x8 bv = *(const bf16x8*)&w2arr[((size_t)f * 64 + lane) * 8];
            bf16x8 a = *(const bf16x8*)&As[cur][(kt * 4 + kb) * SLAB16 + l15 * 8];
            acc = __builtin_amdgcn_mfma_f32_16x16x32_bf16(a, bv, acc, 0, 0, 0);
        }
        __syncthreads();
    }

    // epilogue: f32 z write + per-(b,gblk) BN partials
    int jcol = jq * 16 + l15;
    float s = 0.f, q = 0.f;
#pragma unroll
    for (int r = 0; r < 4; ++r) {  // C/D: col=lane&15, row=(lane>>4)*4+r
        float v = acc[r];
        int g = gbase + kb * 4 + r;
        z[(size_t)(b * G_ + g) * 128 + jcol] = v;
        s += v;
        q += v * v;
    }
    s += __shfl_xor(s, 16, 64); s += __shfl_xor(s, 32, 64);
    q += __shfl_xor(q, 16, 64); q += __shfl_xor(q, 32, 64);
    if (lane < 16) {
        ps[(b * 64 + gblk) * 128 + jcol] = s;
        pq[(b * 64 + gblk) * 128 + jcol] = q;
    }
}

// ---------- BN3 stats: reduce 64 block-partials -> scale/shift per (b,j) ----------
__global__ void k_stats(const float* __restrict__ ps, const float* __restrict__ pq,
                        const float* __restrict__ g3, const float* __restrict__ b3,
                        float* __restrict__ scv, float* __restrict__ shv) {
    int b = blockIdx.x, j = threadIdx.x;
    float s = 0.f, q = 0.f;
#pragma unroll 8
    for (int t = 0; t < 64; ++t) {
        s += ps[(b * 64 + t) * 128 + j];
        q += pq[(b * 64 + t) * 128 + j];
    }
    float mu = s * (1.f / G_);
    float var = q * (1.f / G_) - mu * mu;
    float sc = g3[j] * rsqrtf(var + EPS_);
    scv[b * 128 + j] = sc;
    shv[b * 128 + j] = b3[j] - mu * sc;
}

// ---------- BN3 apply + relu + fc2 dot + sigmoid; one wave per (b,g) ----------
__global__ __launch_bounds__(256) void k_final(const float* __restrict__ z,
                                               const float* __restrict__ scv,
                                               const float* __restrict__ shv,
                                               const float* __restrict__ fc2w,
                                               const float* __restrict__ fc2b,
                                               float* __restrict__ out) {
    int wid = (blockIdx.x * blockDim.x + threadIdx.x) >> 6;
    int lane = threadIdx.x & 63;
    int b = wid >> 10;
    const float* zr = z + (size_t)wid * 128;
    float acc = 0.f;
#pragma unroll
    for (int t = 0; t < 2; ++t) {
        int j = lane + t * 64;
        float v = fmaf(zr[j], scv[b * 128 + j], shv[b * 128 + j]);
        v = fmaxf(v, 0.f);
        acc += v * fc2w[j];
    }
    for (int off = 32; off; off >>= 1) acc += __shfl_down(acc, off, 64);
    if (lane == 0) out[wid] = 1.f / (1.f + expf(-(acc + fc2b[0])));
}

extern "C" void kernel_launch(void* const* d_in, const int* in_sizes, int n_in,
                              void* d_out, int out_size, void* d_ws, size_t ws_size,
                              hipStream_t stream) {
    const int*   gPos = (const int*)d_in[3];
    const float* emb  = (const float*)d_in[4];
    const float* fc_w = (const float*)d_in[11];
    const float* bn3g = (const float*)d_in[13];
    const float* bn3b = (const float*)d_in[14];
    const float* fc2w = (const float*)d_in[15];
    const float* fc2b = (const float*)d_in[16];
    float* out = (float*)d_out;

    char* w = (char*)d_ws;
    float* z     = (float*)w; w += (size_t)B_ * G_ * 128 * 4;   // 4 MB
    short* w2arr = (short*)w; w += (size_t)128 * HD_ * 2;       // 256 KB
    float* ps    = (float*)w; w += (size_t)B_ * 64 * 128 * 4;   // 256 KB
    float* pq    = (float*)w; w += (size_t)B_ * 64 * 128 * 4;   // 256 KB
    float* scv   = (float*)w; w += (size_t)B_ * 128 * 4;
    float* shv   = (float*)w; w += (size_t)B_ * 128 * 4;

    k_w2cvt<<<64, 256, 0, stream>>>(fc_w, w2arr);
    k_gemm<<<dim3(64, B_), 512, 0, stream>>>(gPos, emb, w2arr, z, ps, pq);
    k_stats<<<B_, 128, 0, stream>>>(ps, pq, bn3g, bn3b, scv, shv);
    k_final<<<(B_ * G_) / 4, 256, 0, stream>>>(z, scv, shv, fc2w, fc2b, out);
}